// Round 7
// baseline (443.163 us; speedup 1.0000x reference)
//
#include <hip/hip_runtime.h>

// Input  (16,32,382,255) f32 ; output tensor (16,32,765,765) f32
// + u_min/u_max/v_min/v_max (16 each) written as floats after the tensor.
//
// Gather inversion: out[b,c,u,v] = in[b,c,u+du,v+dv] if in-range else 0,
//   du = (q - r/2) - 255, dv = r - 382  (so valid v-range is [382-r, 637-r)).
// Block-uniform decomposition: each block owns kRows whole output rows of one
// (b,c) plane -> copy-row predicate and column range are uniform; zero rows
// are pure coalesced stores at fill speed.
namespace {
constexpr int kB = 16;
constexpr int kC = 32;
constexpr int kH = 382;   // input rows (AX)
constexpr int kW = 255;   // input cols (EDGE)
constexpr int kS = 765;   // output edge
constexpr int kRows = 5;                     // rows per block; 765 = 5*153
constexpr int kChunks = kS / kRows;          // 153
constexpr int kThreads = 192;                // 3 waves; 192*4 = 768 >= 765
constexpr unsigned long long kOutElems =
    (unsigned long long)kB * kC * (unsigned long long)kS * (unsigned long long)kS;
}

__global__ __launch_bounds__(kThreads) void axial_rows_kernel(
    const float* __restrict__ in, const int* __restrict__ off,
    float* __restrict__ out)
{
    unsigned bid   = blockIdx.x;
    unsigned chunk = bid % (unsigned)kChunks;
    unsigned plane = bid / (unsigned)kChunks;      // b*32 + c
    unsigned b     = plane >> 5;

    // Per-block-uniform offset math (off[] is 128 B, L1-resident).
    int q   = off[2u * b];
    int r   = off[2u * b + 1u];
    int du  = (q - (r >> 1)) - 255;                // h = u + du
    int vlo = 382 - r;                             // first valid v (= -dv)
    int vhi = vlo + kW;                            // one past last valid v

    const float* inplane = in + (size_t)plane * (size_t)(kH * kW);
    float* outchunk = out + (size_t)plane * (size_t)kS * (size_t)kS
                          + (size_t)chunk * (size_t)(kRows * kS);

    int t  = (int)threadIdx.x;
    int u0 = (int)chunk * kRows;

#pragma unroll
    for (int i = 0; i < kRows; ++i) {
        int h = u0 + i + du;
        bool crow = ((unsigned)h < (unsigned)kH);  // row intersects the copy block
        // inrow[v] == in[b,c,h,v-vlo]; pointer only dereferenced when crow.
        const float* inrow =
            inplane + (ptrdiff_t)(crow ? h : 0) * kW - (ptrdiff_t)vlo;
        float* outrow = outchunk + (size_t)i * kS;
#pragma unroll
        for (int j = 0; j < 4; ++j) {
            int v = t + j * kThreads;              // consecutive lanes -> consecutive dwords
            if (j < 3 || v < kS) {
                float val = 0.0f;
                if (crow && v >= vlo && v < vhi) val = inrow[v];
                outrow[v] = val;
            }
        }
    }
}

// u_min = 255 - uoff ; u_max = u_min + 382 ; v_min = 382 - r ; v_max = v_min + 255
__global__ void axial_extras_kernel(const int* __restrict__ off,
                                    float* __restrict__ out_tail)
{
    int i = threadIdx.x;          // 0..63
    if (i >= 64) return;
    int b = i & 15;
    int which = i >> 4;           // 0:u_min 1:u_max 2:v_min 3:v_max
    int q = off[2 * b];
    int r = off[2 * b + 1];
    int uoff = q - (r >> 1);
    int u_min = 255 - uoff;
    int v_min = 382 - r;
    int val = (which == 0) ? u_min
            : (which == 1) ? (u_min + kH)
            : (which == 2) ? v_min
                           : (v_min + kW);
    out_tail[i] = (float)val;
}

extern "C" void kernel_launch(void* const* d_in, const int* in_sizes, int n_in,
                              void* d_out, int out_size, void* d_ws, size_t ws_size,
                              hipStream_t stream) {
    const float* in  = (const float*)d_in[0];
    const int*   off = (const int*)d_in[1];
    float*       out = (float*)d_out;

    unsigned blocks = (unsigned)(kB * kC * kChunks);   // 78,336
    axial_rows_kernel<<<dim3(blocks), dim3(kThreads), 0, stream>>>(in, off, out);
    axial_extras_kernel<<<dim3(1), dim3(64), 0, stream>>>(off, out + kOutElems);
}

// Round 8
// 400.731 us; speedup vs baseline: 1.1059x; 1.1059x over previous
//
#include <hip/hip_runtime.h>

// Input (16,32,382,255) f32 ; output tensor (16,32,765,765) f32
// + u_min/u_max/v_min/v_max (16 each) written as floats after the tensor.
//
// Gather inversion: out[b,c,u,v] = in[b,c,u+du,v+dv] if in-range else 0,
//   du = (q - r/2) - 255 (always < 0), dv = r - 382; valid v in [vlo, vlo+255),
//   vlo = 382 - r.
// Block = one output row of one (b,c) plane -> all offset math block-uniform.
// Stores: 16B-aligned float4 via per-row pad; <=6 head/tail dwords scalar.
namespace {
constexpr int kC = 32;
constexpr int kH = 382;             // input rows (AX)
constexpr int kW = 255;             // input cols (EDGE)
constexpr int kS = 765;             // output edge
constexpr int kPlaneIn  = kH * kW;  // 97410
constexpr int kPlaneOut = kS * kS;  // 585225 (== 1 mod 4 -> row alignment varies)
constexpr unsigned long long kOutElems =
    16ull * kC * (unsigned long long)kPlaneOut;   // 299,635,200
}

__global__ __launch_bounds__(256) void axial_row_kernel(
    const float* __restrict__ in, const int* __restrict__ off,
    float* __restrict__ out)
{
    const unsigned u     = blockIdx.x;   // 0..764 output row
    const unsigned plane = blockIdx.y;   // 0..511  (b*32 + c)
    const unsigned b     = plane >> 5;

    // Block-uniform scalar math (off[] is 128 B, cache-resident).
    const int q   = off[2u * b];
    const int r   = off[2u * b + 1u];
    const int du  = q - (r >> 1) - 255;  // h = u + du
    const int vlo = 382 - r;             // first valid v; valid rel = v - vlo in [0,255)
    const int h   = (int)u + du;
    const bool crow = ((unsigned)h < (unsigned)kH);

    const size_t rowbase = (size_t)plane * (size_t)kPlaneOut + (size_t)u * (size_t)kS;
    float* __restrict__ outrow = out + rowbase;
    const float* __restrict__ inrow =
        in + (size_t)plane * (size_t)kPlaneIn + (size_t)(crow ? h : 0) * (size_t)kW;

    // Align vector stores: first 16B-aligned dword of the row.
    const int pad  = (int)((4u - ((unsigned)rowbase & 3u)) & 3u);
    const int nvec = (kS - pad) >> 2;    // 190 or 191 aligned float4 slots

    const int t = (int)threadIdx.x;
    if (t < nvec) {
        const int d0   = pad + 4 * t;    // dword offset in row, 16B-aligned
        const int rel0 = d0 - vlo;       // input-column of first component
        float v0 = 0.f, v1 = 0.f, v2 = 0.f, v3 = 0.f;
        if (crow) {
            if (rel0 >= 0 && rel0 + 3 < kW) {          // fully inside copy span
                v0 = inrow[rel0];
                v1 = inrow[rel0 + 1];
                v2 = inrow[rel0 + 2];
                v3 = inrow[rel0 + 3];
            } else if (rel0 + 3 >= 0 && rel0 < kW) {   // straddles an edge
                if ((unsigned)(rel0    ) < (unsigned)kW) v0 = inrow[rel0];
                if ((unsigned)(rel0 + 1) < (unsigned)kW) v1 = inrow[rel0 + 1];
                if ((unsigned)(rel0 + 2) < (unsigned)kW) v2 = inrow[rel0 + 2];
                if ((unsigned)(rel0 + 3) < (unsigned)kW) v3 = inrow[rel0 + 3];
            }
        }
        float4 val = {v0, v1, v2, v3};
        *reinterpret_cast<float4*>(outrow + d0) = val;
    } else {
        // head dwords [0,pad) and tail dwords [pad+4*nvec, 765)
        const int s = t - nvec;
        const int d = (s < pad) ? s : (pad + 4 * nvec + (s - pad));
        if (d < kS) {
            float val = 0.f;
            if (crow) {
                const int rel = d - vlo;
                if ((unsigned)rel < (unsigned)kW) val = inrow[rel];
            }
            outrow[d] = val;
        }
    }
}

// u_min = 255 - uoff ; u_max = u_min + 382 ; v_min = 382 - r ; v_max = v_min + 255
__global__ void axial_extras_kernel(const int* __restrict__ off,
                                    float* __restrict__ out_tail)
{
    int i = threadIdx.x;          // 0..63
    if (i >= 64) return;
    int b = i & 15;
    int which = i >> 4;           // 0:u_min 1:u_max 2:v_min 3:v_max
    int q = off[2 * b];
    int r = off[2 * b + 1];
    int uoff = q - (r >> 1);
    int u_min = 255 - uoff;
    int v_min = 382 - r;
    int val = (which == 0) ? u_min
            : (which == 1) ? (u_min + kH)
            : (which == 2) ? v_min
                           : (v_min + kW);
    out_tail[i] = (float)val;
}

extern "C" void kernel_launch(void* const* d_in, const int* in_sizes, int n_in,
                              void* d_out, int out_size, void* d_ws, size_t ws_size,
                              hipStream_t stream) {
    const float* in  = (const float*)d_in[0];
    const int*   off = (const int*)d_in[1];
    float*       out = (float*)d_out;

    axial_row_kernel<<<dim3(kS, 16 * kC), dim3(256), 0, stream>>>(in, off, out);
    axial_extras_kernel<<<dim3(1), dim3(64), 0, stream>>>(off, out + kOutElems);
}